// Round 1
// baseline (1397.677 us; speedup 1.0000x reference)
//
#include <hip/hip_runtime.h>
#include <math.h>

// Problem constants
#define BB 16
#define LQ 576
#define LT 512
#define DD 768
#define HH 12
#define DH 64
#define TOPK 64

// Workspace layout (floats)
static constexpr size_t XQN  = 0;                       // 9216*768   (reused for attn output)
static constexpr size_t XKVN = 7077888;                 // 8192*768
static constexpr size_t QOFF = XKVN + 6291456;          // 9216*768
static constexpr size_t KOFF = QOFF + 7077888;          // 8192*768
static constexpr size_t VOFF = KOFF + 6291456;          // 8192*768
static constexpr size_t KEEP = VOFF + 6291456;          // 192*512
static constexpr size_t GH   = KEEP + 98304;            // 192

// ---------------- LayerNorm: one block per row of 768 ----------------
__global__ __launch_bounds__(256) void ln_kernel(const float* __restrict__ x,
                                                 const float* __restrict__ gg,
                                                 const float* __restrict__ bb,
                                                 float* __restrict__ y) {
  int row = blockIdx.x;
  const float* xr = x + (size_t)row * DD;
  float* yr = y + (size_t)row * DD;
  int t = threadIdx.x;
  float v0 = xr[t], v1 = xr[t + 256], v2 = xr[t + 512];
  __shared__ float red[4];
  float s = v0 + v1 + v2;
  #pragma unroll
  for (int o = 32; o > 0; o >>= 1) s += __shfl_xor(s, o);
  if ((t & 63) == 0) red[t >> 6] = s;
  __syncthreads();
  float m = (red[0] + red[1] + red[2] + red[3]) * (1.0f / 768.0f);
  float d0 = v0 - m, d1 = v1 - m, d2 = v2 - m;
  float s2 = d0 * d0 + d1 * d1 + d2 * d2;
  #pragma unroll
  for (int o = 32; o > 0; o >>= 1) s2 += __shfl_xor(s2, o);
  __syncthreads();
  if ((t & 63) == 0) red[t >> 6] = s2;
  __syncthreads();
  float var = (red[0] + red[1] + red[2] + red[3]) * (1.0f / 768.0f);
  float rs = rsqrtf(var + 1e-5f);
  yr[t]       = d0 * rs * gg[t]       + bb[t];
  yr[t + 256] = d1 * rs * gg[t + 256] + bb[t + 256];
  yr[t + 512] = d2 * rs * gg[t + 512] + bb[t + 512];
}

// ---------------- GEMM: C[M,N] = A[M,K] * W[N,K]^T, optional residual epilogue ----------------
// 128x128 tile, BK=16, 256 threads, 8x8 per thread, f32.
__global__ __launch_bounds__(256) void gemm128(const float* __restrict__ A,
                                               const float* __restrict__ W,
                                               float* __restrict__ C,
                                               int M, int N, int K,
                                               const float* __restrict__ resid,
                                               const float* __restrict__ gl) {
  __shared__ float As[16][132];
  __shared__ float Ws[16][132];
  const int tid = threadIdx.x;
  const int bm = blockIdx.y * 128, bn = blockIdx.x * 128;
  const int tx = tid & 15, ty = tid >> 4;
  float acc[8][8] = {};
  for (int k0 = 0; k0 < K; k0 += 16) {
    #pragma unroll
    for (int i = 0; i < 2; i++) {
      int idx = i * 256 + tid;            // 0..511
      int r = idx >> 2, c4 = (idx & 3) * 4;
      float4 a = *reinterpret_cast<const float4*>(&A[(size_t)(bm + r) * K + k0 + c4]);
      As[c4][r] = a.x; As[c4 + 1][r] = a.y; As[c4 + 2][r] = a.z; As[c4 + 3][r] = a.w;
      float4 w = *reinterpret_cast<const float4*>(&W[(size_t)(bn + r) * K + k0 + c4]);
      Ws[c4][r] = w.x; Ws[c4 + 1][r] = w.y; Ws[c4 + 2][r] = w.z; Ws[c4 + 3][r] = w.w;
    }
    __syncthreads();
    #pragma unroll
    for (int kk = 0; kk < 16; kk++) {
      float a[8], b[8];
      #pragma unroll
      for (int i = 0; i < 8; i++) a[i] = As[kk][ty * 8 + i];
      #pragma unroll
      for (int j = 0; j < 8; j++) b[j] = Ws[kk][tx * 8 + j];
      #pragma unroll
      for (int i = 0; i < 8; i++)
        #pragma unroll
        for (int j = 0; j < 8; j++) acc[i][j] += a[i] * b[j];
    }
    __syncthreads();
  }
  float alpha = 0.0f;
  if (resid) alpha = 1.0f / (1.0f + expf(-gl[0]));
  #pragma unroll
  for (int i = 0; i < 8; i++) {
    int m = bm + ty * 8 + i;
    #pragma unroll
    for (int j = 0; j < 8; j++) {
      int n = bn + tx * 8 + j;
      float val = acc[i][j];
      if (resid) val = resid[(size_t)m * N + n] + alpha * val;
      C[(size_t)m * N + n] = val;
    }
  }
}

// ---------------- Gate + top-k membership: one block (512 threads) per (b,h) ----------------
__global__ __launch_bounds__(512) void gate_topk(const float* __restrict__ Kbuf,
                                                 const float* __restrict__ hq,
                                                 const int* __restrict__ mask,
                                                 float* __restrict__ keep,
                                                 float* __restrict__ g_h) {
  int bh = blockIdx.x, b = bh / HH, h = bh % HH;
  int l = threadIdx.x;
  __shared__ float s_sc[512];
  __shared__ float s_p[512];
  __shared__ float s_c[64];
  __shared__ float red[8];
  const float scale = 0.125f;
  const float* kr = Kbuf + ((size_t)(b * LT + l)) * DD + h * DH;
  float sc = 0.0f;
  #pragma unroll
  for (int d = 0; d < DH; d += 4) {
    float4 kk = *reinterpret_cast<const float4*>(kr + d);
    float4 qq = *reinterpret_cast<const float4*>(hq + h * DH + d);
    sc += kk.x * qq.x + kk.y * qq.y + kk.z * qq.z + kk.w * qq.w;
  }
  sc *= scale;
  if (mask[b * LT + l] == 0) sc = -INFINITY;
  s_sc[l] = sc;
  __syncthreads();
  // block max
  float m = sc;
  #pragma unroll
  for (int o = 32; o > 0; o >>= 1) m = fmaxf(m, __shfl_xor(m, o));
  if ((l & 63) == 0) red[l >> 6] = m;
  __syncthreads();
  m = red[0];
  #pragma unroll
  for (int w = 1; w < 8; w++) m = fmaxf(m, red[w]);
  float p = expf(sc - m);
  float ssum = p;
  #pragma unroll
  for (int o = 32; o > 0; o >>= 1) ssum += __shfl_xor(ssum, o);
  __syncthreads();
  if ((l & 63) == 0) red[l >> 6] = ssum;
  __syncthreads();
  float Z = 0.0f;
  #pragma unroll
  for (int w = 0; w < 8; w++) Z += red[w];
  p /= Z;
  s_p[l] = p;
  __syncthreads();
  if (l < 64) {
    float c = 0.0f;
    for (int t = 0; t < LT; t++) c += s_p[t] * Kbuf[((size_t)(b * LT + t)) * DD + h * DH + l];
    s_c[l] = c * hq[h * DH + l];
  }
  __syncthreads();
  if (l == 0) {
    float glog = 0.0f;
    for (int d = 0; d < DH; d++) glog += s_c[d];
    glog *= scale;
    g_h[bh] = 1.0f / (1.0f + expf(-glog));
  }
  // top-k membership (stable ties, matches jax.lax.top_k)
  float my = s_sc[l];
  int cnt = 0;
  for (int j = 0; j < LT; j++) {
    float sj = s_sc[j];
    cnt += (sj > my || (sj == my && j < l)) ? 1 : 0;
  }
  keep[(size_t)bh * LT + l] = (cnt < TOPK) ? 1.0f : 0.0f;
}

// ---------------- Attention: one block per (q-tile of 16, b*h) ----------------
#define QT 16
__global__ __launch_bounds__(256) void attn_kernel(const float* __restrict__ Q,
                                                   const float* __restrict__ Kb,
                                                   const float* __restrict__ Vb,
                                                   const float* __restrict__ keep,
                                                   const float* __restrict__ g_h,
                                                   const int* __restrict__ mask,
                                                   float* __restrict__ att) {
  int bh = blockIdx.y, b = bh / HH, h = bh % HH;
  int q0 = blockIdx.x * QT;
  int tid = threadIdx.x;
  __shared__ float qs[QT][68];
  __shared__ float sc[QT][516];
  __shared__ float stage[128][68];
  __shared__ float kl[512];
  // load q tile
  #pragma unroll
  for (int i = 0; i < 4; i++) {
    int idx = i * 256 + tid;
    int r = idx >> 6, d = idx & 63;
    qs[r][d] = Q[((size_t)(b * LQ + q0 + r)) * DD + h * DH + d];
  }
  // keep & valid encoded: -1 invalid, 0 dropped, 1 kept
  #pragma unroll
  for (int i = 0; i < 2; i++) {
    int t = i * 256 + tid;
    float kv = keep[(size_t)bh * LT + t];
    kl[t] = (mask[b * LT + t] == 0) ? -1.0f : kv;
  }
  __syncthreads();
  const float scale = 0.125f;
  int tloc = tid & 127, rbase = tid >> 7;
  for (int kc = 0; kc < 4; kc++) {
    #pragma unroll
    for (int i = 0; i < 8; i++) {
      int idx = i * 256 + tid;          // 2048 float4
      int tt = idx >> 4, d4 = idx & 15;
      float4 kk = *reinterpret_cast<const float4*>(
          &Kb[((size_t)(b * LT + kc * 128 + tt)) * DD + h * DH + d4 * 4]);
      stage[tt][d4 * 4 + 0] = kk.x; stage[tt][d4 * 4 + 1] = kk.y;
      stage[tt][d4 * 4 + 2] = kk.z; stage[tt][d4 * 4 + 3] = kk.w;
    }
    __syncthreads();
    float dot[8] = {0, 0, 0, 0, 0, 0, 0, 0};
    #pragma unroll
    for (int d4 = 0; d4 < 16; d4++) {
      float4 s4 = *reinterpret_cast<const float4*>(&stage[tloc][d4 * 4]);
      #pragma unroll
      for (int rr = 0; rr < 8; rr++) {
        float4 q4 = *reinterpret_cast<const float4*>(&qs[rr * 2 + rbase][d4 * 4]);
        dot[rr] += q4.x * s4.x + q4.y * s4.y + q4.z * s4.z + q4.w * s4.w;
      }
    }
    int t = kc * 128 + tloc;
    float f = kl[t];
    #pragma unroll
    for (int rr = 0; rr < 8; rr++) {
      float sval = (f < 0.0f) ? -INFINITY : (f > 0.0f ? dot[rr] * scale : 0.0f);
      sc[rr * 2 + rbase][t] = sval;
    }
    __syncthreads();
  }
  // softmax: 16 threads per row
  {
    int r = tid >> 4, ln = tid & 15;
    float mx = -INFINITY;
    for (int t = ln; t < LT; t += 16) mx = fmaxf(mx, sc[r][t]);
    #pragma unroll
    for (int o = 8; o > 0; o >>= 1) mx = fmaxf(mx, __shfl_xor(mx, o));
    float sum = 0.0f;
    for (int t = ln; t < LT; t += 16) sum += expf(sc[r][t] - mx);
    #pragma unroll
    for (int o = 8; o > 0; o >>= 1) sum += __shfl_xor(sum, o);
    float inv = 1.0f / sum;
    for (int t = ln; t < LT; t += 16) {
      float p = expf(sc[r][t] - mx) * inv;
      sc[r][t] = (kl[t] > 0.0f) ? p : 0.0f;   // zero dropped/invalid for PV
    }
  }
  __syncthreads();
  // PV
  int r = tid >> 4, dg = tid & 15;
  float4 oa = make_float4(0, 0, 0, 0);
  for (int kc = 0; kc < 4; kc++) {
    #pragma unroll
    for (int i = 0; i < 8; i++) {
      int idx = i * 256 + tid;
      int tt = idx >> 4, d4 = idx & 15;
      float4 vv = *reinterpret_cast<const float4*>(
          &Vb[((size_t)(b * LT + kc * 128 + tt)) * DD + h * DH + d4 * 4]);
      stage[tt][d4 * 4 + 0] = vv.x; stage[tt][d4 * 4 + 1] = vv.y;
      stage[tt][d4 * 4 + 2] = vv.z; stage[tt][d4 * 4 + 3] = vv.w;
    }
    __syncthreads();
    for (int t = 0; t < 128; t++) {
      float p = sc[r][kc * 128 + t];
      float4 v4 = *reinterpret_cast<const float4*>(&stage[t][dg * 4]);
      oa.x += p * v4.x; oa.y += p * v4.y; oa.z += p * v4.z; oa.w += p * v4.w;
    }
    __syncthreads();
  }
  float g = g_h[bh];
  float4 ov = make_float4(oa.x * g, oa.y * g, oa.z * g, oa.w * g);
  *reinterpret_cast<float4*>(&att[((size_t)(b * LQ + q0 + r)) * DD + h * DH + dg * 4]) = ov;
}

extern "C" void kernel_launch(void* const* d_in, const int* in_sizes, int n_in,
                              void* d_out, int out_size, void* d_ws, size_t ws_size,
                              hipStream_t stream) {
  const float* x_q      = (const float*)d_in[0];
  const float* x_kv     = (const float*)d_in[1];
  const int*   mask     = (const int*)d_in[2];
  const float* wq       = (const float*)d_in[3];
  const float* wk       = (const float*)d_in[4];
  const float* wv       = (const float*)d_in[5];
  const float* wo       = (const float*)d_in[6];
  const float* ln_q_g   = (const float*)d_in[7];
  const float* ln_q_b   = (const float*)d_in[8];
  const float* ln_kv_g  = (const float*)d_in[9];
  const float* ln_kv_b  = (const float*)d_in[10];
  const float* hq       = (const float*)d_in[11];
  const float* resid_l  = (const float*)d_in[12];
  float* out = (float*)d_out;
  float* ws  = (float*)d_ws;

  // LayerNorms
  ln_kernel<<<dim3(BB * LQ), dim3(256), 0, stream>>>(x_q, ln_q_g, ln_q_b, ws + XQN);
  ln_kernel<<<dim3(BB * LT), dim3(256), 0, stream>>>(x_kv, ln_kv_g, ln_kv_b, ws + XKVN);
  // Projections
  gemm128<<<dim3(6, 72), dim3(256), 0, stream>>>(ws + XQN,  wq, ws + QOFF, BB * LQ, DD, DD, nullptr, nullptr);
  gemm128<<<dim3(6, 64), dim3(256), 0, stream>>>(ws + XKVN, wk, ws + KOFF, BB * LT, DD, DD, nullptr, nullptr);
  gemm128<<<dim3(6, 64), dim3(256), 0, stream>>>(ws + XKVN, wv, ws + VOFF, BB * LT, DD, DD, nullptr, nullptr);
  // Gate + top-k
  gate_topk<<<dim3(BB * HH), dim3(512), 0, stream>>>(ws + KOFF, hq, mask, ws + KEEP, ws + GH);
  // Attention (writes into XQN slot, which is free after Q projection)
  attn_kernel<<<dim3(LQ / QT, BB * HH), dim3(256), 0, stream>>>(
      ws + QOFF, ws + KOFF, ws + VOFF, ws + KEEP, ws + GH, mask, ws + XQN);
  // Output projection + residual
  gemm128<<<dim3(6, 72), dim3(256), 0, stream>>>(ws + XQN, wo, out, BB * LQ, DD, DD, x_q, resid_l);
}

// Round 2
// 755.008 us; speedup vs baseline: 1.8512x; 1.8512x over previous
//
#include <hip/hip_runtime.h>
#include <math.h>

// Problem constants
#define BB 16
#define LQ 576
#define LT 512
#define DD 768
#define HH 12
#define DH 64
#define TOPK 64

typedef __attribute__((ext_vector_type(8))) short bf16x8;
typedef __attribute__((ext_vector_type(4))) float f32x4;

// Workspace layout (float offsets)
static constexpr size_t XQN  = 0;                        // 9216*768 f32 (xq_n, reused for attn out)
static constexpr size_t XKVN = 7077888;                  // 8192*768 f32
static constexpr size_t KF32 = XKVN + 6291456;           // 8192*768 f32 (K for gate/topk)
static constexpr size_t QBFo = KF32 + 6291456;           // 9216*768 bf16 = 3538944 f
static constexpr size_t KBFo = QBFo + 3538944;           // 8192*768 bf16 = 3145728 f
static constexpr size_t VTBo = KBFo + 3145728;           // [192][64][512] bf16 = 3145728 f
static constexpr size_t KEEP = VTBo + 3145728;           // 192*512 f32
static constexpr size_t GH   = KEEP + 98304;             // 192 f32

__device__ inline unsigned short f2bf(float f) {
  union { float f; unsigned u; } v; v.f = f;
  unsigned r = v.u + 0x7FFFu + ((v.u >> 16) & 1u);
  return (unsigned short)(r >> 16);
}

__device__ inline void gload_lds16(const void* src, void* dst) {
  __builtin_amdgcn_global_load_lds((const __attribute__((address_space(1))) void*)src,
                                   (__attribute__((address_space(3))) void*)dst, 16, 0, 0);
}

// ---------------- LayerNorm ----------------
__global__ __launch_bounds__(256) void ln_kernel(const float* __restrict__ x,
                                                 const float* __restrict__ gg,
                                                 const float* __restrict__ bb,
                                                 float* __restrict__ y) {
  int row = blockIdx.x;
  const float* xr = x + (size_t)row * DD;
  float* yr = y + (size_t)row * DD;
  int t = threadIdx.x;
  float v0 = xr[t], v1 = xr[t + 256], v2 = xr[t + 512];
  __shared__ float red[4];
  float s = v0 + v1 + v2;
  #pragma unroll
  for (int o = 32; o > 0; o >>= 1) s += __shfl_xor(s, o);
  if ((t & 63) == 0) red[t >> 6] = s;
  __syncthreads();
  float m = (red[0] + red[1] + red[2] + red[3]) * (1.0f / 768.0f);
  float d0 = v0 - m, d1 = v1 - m, d2 = v2 - m;
  float s2 = d0 * d0 + d1 * d1 + d2 * d2;
  #pragma unroll
  for (int o = 32; o > 0; o >>= 1) s2 += __shfl_xor(s2, o);
  __syncthreads();
  if ((t & 63) == 0) red[t >> 6] = s2;
  __syncthreads();
  float var = (red[0] + red[1] + red[2] + red[3]) * (1.0f / 768.0f);
  float rs = rsqrtf(var + 1e-5f);
  yr[t]       = d0 * rs * gg[t]       + bb[t];
  yr[t + 256] = d1 * rs * gg[t + 256] + bb[t + 256];
  yr[t + 512] = d2 * rs * gg[t + 512] + bb[t + 512];
}

// ---------------- f32 GEMM: C = A[M,K] * W[N,K]^T with multi-format epilogue ----------------
__global__ __launch_bounds__(256) void gemm128(const float* __restrict__ A,
                                               const float* __restrict__ W,
                                               float* __restrict__ Cf,
                                               unsigned short* __restrict__ Cb,
                                               unsigned short* __restrict__ Cvt,
                                               int M, int N, int K,
                                               const float* __restrict__ resid,
                                               const float* __restrict__ gl) {
  __shared__ float As[16][132];
  __shared__ float Ws[16][132];
  const int tid = threadIdx.x;
  const int bm = blockIdx.y * 128, bn = blockIdx.x * 128;
  const int tx = tid & 15, ty = tid >> 4;
  float acc[8][8] = {};
  for (int k0 = 0; k0 < K; k0 += 16) {
    #pragma unroll
    for (int i = 0; i < 2; i++) {
      int idx = i * 256 + tid;
      int r = idx >> 2, c4 = (idx & 3) * 4;
      float4 a = *reinterpret_cast<const float4*>(&A[(size_t)(bm + r) * K + k0 + c4]);
      As[c4][r] = a.x; As[c4 + 1][r] = a.y; As[c4 + 2][r] = a.z; As[c4 + 3][r] = a.w;
      float4 w = *reinterpret_cast<const float4*>(&W[(size_t)(bn + r) * K + k0 + c4]);
      Ws[c4][r] = w.x; Ws[c4 + 1][r] = w.y; Ws[c4 + 2][r] = w.z; Ws[c4 + 3][r] = w.w;
    }
    __syncthreads();
    #pragma unroll
    for (int kk = 0; kk < 16; kk++) {
      float a[8], b[8];
      #pragma unroll
      for (int i = 0; i < 8; i++) a[i] = As[kk][ty * 8 + i];
      #pragma unroll
      for (int j = 0; j < 8; j++) b[j] = Ws[kk][tx * 8 + j];
      #pragma unroll
      for (int i = 0; i < 8; i++)
        #pragma unroll
        for (int j = 0; j < 8; j++) acc[i][j] += a[i] * b[j];
    }
    __syncthreads();
  }
  float alpha = 0.0f;
  if (resid) alpha = 1.0f / (1.0f + __expf(-gl[0]));
  #pragma unroll
  for (int i = 0; i < 8; i++) {
    int m = bm + ty * 8 + i;
    if (Cf) {
      #pragma unroll
      for (int j = 0; j < 8; j++) {
        int n = bn + tx * 8 + j;
        float val = acc[i][j];
        if (resid) val = resid[(size_t)m * N + n] + alpha * val;
        Cf[(size_t)m * N + n] = val;
      }
    }
    if (Cb) {
      bf16x8 v;
      #pragma unroll
      for (int j = 0; j < 8; j++) v[j] = (short)f2bf(acc[i][j]);
      *reinterpret_cast<bf16x8*>(&Cb[(size_t)m * N + bn + tx * 8]) = v;
    }
  }
  if (Cvt) {
    // V^T layout: [b*12+h][d(64)][t(512)] bf16
    int m0 = bm + ty * 8;
    int bidx = m0 >> 9, t_lo = m0 & 511;
    #pragma unroll
    for (int j = 0; j < 8; j++) {
      int n = bn + tx * 8 + j;
      int hh = n >> 6, d = n & 63;
      bf16x8 v;
      #pragma unroll
      for (int i = 0; i < 8; i++) v[i] = (short)f2bf(acc[i][j]);
      size_t idx = (((size_t)bidx * HH + hh) * DH + d) * LT + t_lo;
      *reinterpret_cast<bf16x8*>(&Cvt[idx]) = v;
    }
  }
}

// ---------------- Gate + top-k (f32 K) ----------------
__global__ __launch_bounds__(512) void gate_topk(const float* __restrict__ Kbuf,
                                                 const float* __restrict__ hq,
                                                 const int* __restrict__ mask,
                                                 float* __restrict__ keep,
                                                 float* __restrict__ g_h) {
  int bh = blockIdx.x, b = bh / HH, h = bh % HH;
  int l = threadIdx.x;
  __shared__ float s_sc[512];
  __shared__ float s_p[512];
  __shared__ float s_c[64];
  __shared__ float red[8];
  const float scale = 0.125f;
  const float* kr = Kbuf + ((size_t)(b * LT + l)) * DD + h * DH;
  float sc = 0.0f;
  #pragma unroll
  for (int d = 0; d < DH; d += 4) {
    float4 kk = *reinterpret_cast<const float4*>(kr + d);
    float4 qq = *reinterpret_cast<const float4*>(hq + h * DH + d);
    sc += kk.x * qq.x + kk.y * qq.y + kk.z * qq.z + kk.w * qq.w;
  }
  sc *= scale;
  if (mask[b * LT + l] == 0) sc = -INFINITY;
  s_sc[l] = sc;
  __syncthreads();
  float m = sc;
  #pragma unroll
  for (int o = 32; o > 0; o >>= 1) m = fmaxf(m, __shfl_xor(m, o));
  if ((l & 63) == 0) red[l >> 6] = m;
  __syncthreads();
  m = red[0];
  #pragma unroll
  for (int w = 1; w < 8; w++) m = fmaxf(m, red[w]);
  float p = expf(sc - m);
  float ssum = p;
  #pragma unroll
  for (int o = 32; o > 0; o >>= 1) ssum += __shfl_xor(ssum, o);
  __syncthreads();
  if ((l & 63) == 0) red[l >> 6] = ssum;
  __syncthreads();
  float Z = 0.0f;
  #pragma unroll
  for (int w = 0; w < 8; w++) Z += red[w];
  p /= Z;
  s_p[l] = p;
  __syncthreads();
  if (l < 64) {
    float c = 0.0f;
    for (int t = 0; t < LT; t++) c += s_p[t] * Kbuf[((size_t)(b * LT + t)) * DD + h * DH + l];
    s_c[l] = c * hq[h * DH + l];
  }
  __syncthreads();
  if (l == 0) {
    float glog = 0.0f;
    for (int d = 0; d < DH; d++) glog += s_c[d];
    glog *= scale;
    g_h[bh] = 1.0f / (1.0f + expf(-glog));
  }
  float my = s_sc[l];
  int cnt = 0;
  for (int j = 0; j < LT; j++) {
    float sj = s_sc[j];
    cnt += (sj > my || (sj == my && j < l)) ? 1 : 0;
  }
  keep[(size_t)bh * LT + l] = (cnt < TOPK) ? 1.0f : 0.0f;
}

// ---------------- MFMA flash attention ----------------
// Block: (q-tile 64, bh). 4 waves x 16 q-rows. Chunks of 64 keys.
__global__ __launch_bounds__(256) void attn_mfma(const unsigned short* __restrict__ Qb,
                                                 const unsigned short* __restrict__ Kb,
                                                 const unsigned short* __restrict__ Vt,
                                                 const float* __restrict__ keep,
                                                 const float* __restrict__ g_h,
                                                 const int* __restrict__ mask,
                                                 float* __restrict__ att) {
  const int bh = blockIdx.y, b = bh / HH, h = bh % HH;
  const int q0 = blockIdx.x * 64;
  const int tid = threadIdx.x;
  const int w = tid >> 6, l = tid & 63;
  const int lq = l & 15, g = l >> 4;

  __shared__ __align__(16) unsigned short Klds[64 * 64];   // [key][d] swizzled
  __shared__ __align__(16) unsigned short Vlds[64 * 64];   // [d][t] swizzled
  __shared__ __align__(16) unsigned short Plds[4][16][72];
  __shared__ float kl[64];

  // Q fragments (B-operand of swapped QK^T): lane reads Q row (l&15), 8 consecutive d
  bf16x8 qf0, qf1;
  {
    const unsigned short* qrow =
        Qb + ((size_t)(b * LQ + q0 + w * 16 + lq)) * DD + h * DH + g * 8;
    qf0 = *reinterpret_cast<const bf16x8*>(qrow);
    qf1 = *reinterpret_cast<const bf16x8*>(qrow + 32);
  }

  f32x4 O[4] = {};
  float m_run = -INFINITY, l_run = 0.0f;

  const unsigned short* Kg0 = Kb + ((size_t)(b * LT)) * DD + h * DH;
  const unsigned short* Vg0 = Vt + ((size_t)bh * DH) * LT;

  for (int t0 = 0; t0 < LT; t0 += 64) {
    if (tid < 64) {
      int t = t0 + tid;
      float kv = keep[(size_t)bh * LT + t];
      kl[tid] = (mask[b * LT + t] == 0) ? -1.0f : kv;
    }
    // stage K chunk [64 keys][64 d] and V^T chunk [64 d][64 t], XOR-swizzled via source
    #pragma unroll
    for (int it = 0; it < 2; ++it) {
      int row = w * 16 + it * 8 + (l >> 3);
      int col = ((l & 7) * 16) ^ (((l >> 3) & 7) << 4);   // byte col in 128B row
      gload_lds16(Kg0 + (size_t)(t0 + row) * DD + (col >> 1),
                  &Klds[(w * 16 + it * 8) * 64]);
      gload_lds16(Vg0 + (size_t)row * LT + t0 + (col >> 1),
                  &Vlds[(w * 16 + it * 8) * 64]);
    }
    __syncthreads();

    // S^T[64 keys, 16 q]: 4 key-subtiles of 16
    f32x4 S[4];
    #pragma unroll
    for (int kt = 0; kt < 4; ++kt) {
      f32x4 acc = {};
      int row = kt * 16 + lq;
      int c0 = (g * 16) ^ ((row & 7) << 4);
      int c1 = (64 + g * 16) ^ ((row & 7) << 4);
      bf16x8 a0 = *reinterpret_cast<const bf16x8*>(&Klds[row * 64 + (c0 >> 1)]);
      bf16x8 a1 = *reinterpret_cast<const bf16x8*>(&Klds[row * 64 + (c1 >> 1)]);
      acc = __builtin_amdgcn_mfma_f32_16x16x32_bf16(a0, qf0, acc, 0, 0, 0);
      acc = __builtin_amdgcn_mfma_f32_16x16x32_bf16(a1, qf1, acc, 0, 0, 0);
      S[kt] = acc;
    }

    // online softmax: lane owns q=lq, 16 of the 64 keys
    float cmax = -INFINITY;
    #pragma unroll
    for (int kt = 0; kt < 4; ++kt)
      #pragma unroll
      for (int r = 0; r < 4; ++r) {
        float c = kl[kt * 16 + g * 4 + r];
        float s = (c > 0.5f) ? S[kt][r] * 0.125f : (c < -0.5f ? -INFINITY : 0.0f);
        cmax = fmaxf(cmax, s);
      }
    cmax = fmaxf(cmax, __shfl_xor(cmax, 16));
    cmax = fmaxf(cmax, __shfl_xor(cmax, 32));
    float m_new = fmaxf(m_run, cmax);
    float fac = (m_new == -INFINITY) ? 1.0f : __expf(m_run - m_new);

    float psum = 0.0f;
    #pragma unroll
    for (int kt = 0; kt < 4; ++kt)
      #pragma unroll
      for (int r = 0; r < 4; ++r) {
        int key = kt * 16 + g * 4 + r;
        float c = kl[key];
        float s = (c > 0.5f) ? S[kt][r] * 0.125f : (c < -0.5f ? -INFINITY : 0.0f);
        float p = __expf(s - m_new);
        psum += p;
        Plds[w][lq][key] = f2bf((c > 0.5f) ? p : 0.0f);
      }
    psum += __shfl_xor(psum, 16);
    psum += __shfl_xor(psum, 32);
    l_run = l_run * fac + psum;
    m_run = m_new;

    // rescale O (O-lane holds q rows g*4+r)
    float facO[4];
    #pragma unroll
    for (int r = 0; r < 4; ++r) facO[r] = __shfl(fac, g * 4 + r);
    #pragma unroll
    for (int dt = 0; dt < 4; ++dt)
      #pragma unroll
      for (int r = 0; r < 4; ++r) O[dt][r] *= facO[r];

    __syncthreads();  // P visible; K/V reads of this chunk done before next stage? (K done; V below)

    // PV: O[16q, 64d] += P[16q,32k] * V[32k,16d], two k-steps
    #pragma unroll
    for (int ks = 0; ks < 2; ++ks) {
      bf16x8 pa = *reinterpret_cast<const bf16x8*>(&Plds[w][lq][ks * 32 + g * 8]);
      #pragma unroll
      for (int dt = 0; dt < 4; ++dt) {
        int row = dt * 16 + lq;
        int cb = (ks * 64 + g * 16) ^ ((row & 7) << 4);
        bf16x8 vb = *reinterpret_cast<const bf16x8*>(&Vlds[row * 64 + (cb >> 1)]);
        O[dt] = __builtin_amdgcn_mfma_f32_16x16x32_bf16(pa, vb, O[dt], 0, 0, 0);
      }
    }
    __syncthreads();
  }

  float inv = 1.0f / l_run;
  float invl[4];
  #pragma unroll
  for (int r = 0; r < 4; ++r) invl[r] = __shfl(inv, g * 4 + r);
  float gh = g_h[bh];
  #pragma unroll
  for (int dt = 0; dt < 4; ++dt)
    #pragma unroll
    for (int r = 0; r < 4; ++r) {
      int q = q0 + w * 16 + g * 4 + r;
      att[((size_t)(b * LQ + q)) * DD + h * DH + dt * 16 + lq] = O[dt][r] * invl[r] * gh;
    }
}

extern "C" void kernel_launch(void* const* d_in, const int* in_sizes, int n_in,
                              void* d_out, int out_size, void* d_ws, size_t ws_size,
                              hipStream_t stream) {
  const float* x_q      = (const float*)d_in[0];
  const float* x_kv     = (const float*)d_in[1];
  const int*   mask     = (const int*)d_in[2];
  const float* wq       = (const float*)d_in[3];
  const float* wk       = (const float*)d_in[4];
  const float* wv       = (const float*)d_in[5];
  const float* wo       = (const float*)d_in[6];
  const float* ln_q_g   = (const float*)d_in[7];
  const float* ln_q_b   = (const float*)d_in[8];
  const float* ln_kv_g  = (const float*)d_in[9];
  const float* ln_kv_b  = (const float*)d_in[10];
  const float* hq       = (const float*)d_in[11];
  const float* resid_l  = (const float*)d_in[12];
  float* out = (float*)d_out;
  float* ws  = (float*)d_ws;

  unsigned short* QBF = (unsigned short*)(ws + QBFo);
  unsigned short* KBF = (unsigned short*)(ws + KBFo);
  unsigned short* VTB = (unsigned short*)(ws + VTBo);

  ln_kernel<<<dim3(BB * LQ), dim3(256), 0, stream>>>(x_q, ln_q_g, ln_q_b, ws + XQN);
  ln_kernel<<<dim3(BB * LT), dim3(256), 0, stream>>>(x_kv, ln_kv_g, ln_kv_b, ws + XKVN);

  gemm128<<<dim3(6, 72), dim3(256), 0, stream>>>(ws + XQN,  wq, nullptr, QBF, nullptr,
                                                 BB * LQ, DD, DD, nullptr, nullptr);
  gemm128<<<dim3(6, 64), dim3(256), 0, stream>>>(ws + XKVN, wk, ws + KF32, KBF, nullptr,
                                                 BB * LT, DD, DD, nullptr, nullptr);
  gemm128<<<dim3(6, 64), dim3(256), 0, stream>>>(ws + XKVN, wv, nullptr, nullptr, VTB,
                                                 BB * LT, DD, DD, nullptr, nullptr);

  gate_topk<<<dim3(BB * HH), dim3(512), 0, stream>>>(ws + KF32, hq, mask, ws + KEEP, ws + GH);

  attn_mfma<<<dim3(LQ / 64, BB * HH), dim3(256), 0, stream>>>(QBF, KBF, VTB,
                                                              ws + KEEP, ws + GH, mask, ws + XQN);

  gemm128<<<dim3(6, 72), dim3(256), 0, stream>>>(ws + XQN, wo, out, nullptr, nullptr,
                                                 BB * LQ, DD, DD, x_q, resid_l);
}

// Round 3
// 209.859 us; speedup vs baseline: 6.6601x; 3.5977x over previous
//
#include <hip/hip_runtime.h>
#include <math.h>

// Problem constants
#define BB 16
#define LQ 576
#define LT 512
#define DD 768
#define HH 12
#define DH 64
#define TOPK 64

typedef __attribute__((ext_vector_type(8))) short bf16x8;
typedef __attribute__((ext_vector_type(4))) float f32x4;
typedef __attribute__((ext_vector_type(4))) unsigned short u16x4;

// Workspace layout (float offsets)
static constexpr size_t XQBF  = 0;          // 9216*768 bf16 = 3538944 f
static constexpr size_t XKVBF = 3538944;    // 8192*768 bf16 = 3145728 f
static constexpr size_t WQB   = 6684672;    // 768*768 bf16 = 294912 f
static constexpr size_t WKB   = 6979584;
static constexpr size_t WVB   = 7274496;
static constexpr size_t WOB   = 7569408;
static constexpr size_t QBFo  = 7864320;    // 9216*768 bf16
static constexpr size_t KBFo  = 11403264;   // 8192*768 bf16
static constexpr size_t VTBo  = 14548992;   // [192][64][512] bf16
static constexpr size_t ABFo  = 17694720;   // 9216*768 bf16 (attn out)
static constexpr size_t KEEP  = 21233664;   // 192*512 f32
static constexpr size_t GH    = 21331968;   // 192 f32

__device__ inline unsigned short f2bf(float f) {
  union { float f; unsigned u; } v; v.f = f;
  unsigned r = v.u + 0x7FFFu + ((v.u >> 16) & 1u);
  return (unsigned short)(r >> 16);
}
__device__ inline float bf2f(unsigned short u) {
  union { unsigned u; float f; } v; v.u = ((unsigned)u) << 16;
  return v.f;
}
__device__ inline void gload_lds16(const void* src, void* dst) {
  __builtin_amdgcn_global_load_lds((const __attribute__((address_space(1))) void*)src,
                                   (__attribute__((address_space(3))) void*)dst, 16, 0, 0);
}

// ---------------- LayerNorm -> bf16 ----------------
__global__ __launch_bounds__(256) void ln_bf16(const float* __restrict__ x,
                                               const float* __restrict__ gg,
                                               const float* __restrict__ bb,
                                               unsigned short* __restrict__ y) {
  int row = blockIdx.x;
  const float* xr = x + (size_t)row * DD;
  unsigned short* yr = y + (size_t)row * DD;
  int t = threadIdx.x;
  float v0 = xr[t], v1 = xr[t + 256], v2 = xr[t + 512];
  __shared__ float red[4];
  float s = v0 + v1 + v2;
  #pragma unroll
  for (int o = 32; o > 0; o >>= 1) s += __shfl_xor(s, o);
  if ((t & 63) == 0) red[t >> 6] = s;
  __syncthreads();
  float m = (red[0] + red[1] + red[2] + red[3]) * (1.0f / 768.0f);
  float d0 = v0 - m, d1 = v1 - m, d2 = v2 - m;
  float s2 = d0 * d0 + d1 * d1 + d2 * d2;
  #pragma unroll
  for (int o = 32; o > 0; o >>= 1) s2 += __shfl_xor(s2, o);
  __syncthreads();
  if ((t & 63) == 0) red[t >> 6] = s2;
  __syncthreads();
  float var = (red[0] + red[1] + red[2] + red[3]) * (1.0f / 768.0f);
  float rs = rsqrtf(var + 1e-5f);
  yr[t]       = f2bf(d0 * rs * gg[t]       + bb[t]);
  yr[t + 256] = f2bf(d1 * rs * gg[t + 256] + bb[t + 256]);
  yr[t + 512] = f2bf(d2 * rs * gg[t + 512] + bb[t + 512]);
}

// ---------------- f32 -> bf16 weight convert ----------------
__global__ __launch_bounds__(256) void conv_bf16(const float* __restrict__ src,
                                                 unsigned short* __restrict__ dst, int n) {
  int i = (blockIdx.x * 256 + threadIdx.x) * 4;
  if (i < n) {
    float4 v = *reinterpret_cast<const float4*>(&src[i]);
    u16x4 o = { f2bf(v.x), f2bf(v.y), f2bf(v.z), f2bf(v.w) };
    *reinterpret_cast<u16x4*>(&dst[i]) = o;
  }
}

// ---------------- bf16 MFMA GEMM: C = A[M,K] * W[N,K]^T (N=768) ----------------
// 128x128 tile, BK=64, 4 waves (2x2), 4x4 fragments each. m97-style staging.
__global__ __launch_bounds__(256) void gemm_bf16(const unsigned short* __restrict__ A,
                                                 const unsigned short* __restrict__ W,
                                                 int M, int K,
                                                 unsigned short* __restrict__ Crm,
                                                 unsigned short* __restrict__ Cvt,
                                                 float* __restrict__ Cf,
                                                 const float* __restrict__ resid,
                                                 const float* __restrict__ gl) {
  __shared__ __align__(16) unsigned short As[128 * 64];
  __shared__ __align__(16) unsigned short Bs[128 * 64];
  const int tid = threadIdx.x;
  const int w = tid >> 6, l = tid & 63;
  const int bm = blockIdx.y * 128, bn = blockIdx.x * 128;
  const int wr = w >> 1, wc = w & 1;
  const int lq = l & 15, g = l >> 4;
  f32x4 acc[4][4] = {};
  // staging: lane covers row (l>>3) of an 8-row group, 16B at swizzled source col
  const int srow = l >> 3;
  const int scol = ((l & 7) * 16) ^ ((srow & 7) << 4);   // byte col within 128B row

  for (int k0 = 0; k0 < K; k0 += 64) {
    #pragma unroll
    for (int it = 0; it < 4; ++it) {
      int rbase = it * 32 + w * 8;
      gload_lds16(A + (size_t)(bm + rbase + srow) * K + k0 + (scol >> 1), &As[rbase * 64]);
      gload_lds16(W + (size_t)(bn + rbase + srow) * K + k0 + (scol >> 1), &Bs[rbase * 64]);
    }
    __syncthreads();
    #pragma unroll
    for (int ks = 0; ks < 2; ++ks) {
      bf16x8 a[4], b[4];
      #pragma unroll
      for (int mi = 0; mi < 4; ++mi) {
        int row = wr * 64 + mi * 16 + lq;
        int cb = (ks * 64 + g * 16) ^ ((row & 7) << 4);
        a[mi] = *reinterpret_cast<const bf16x8*>(&As[row * 64 + (cb >> 1)]);
      }
      #pragma unroll
      for (int ni = 0; ni < 4; ++ni) {
        int row = wc * 64 + ni * 16 + lq;
        int cb = (ks * 64 + g * 16) ^ ((row & 7) << 4);
        b[ni] = *reinterpret_cast<const bf16x8*>(&Bs[row * 64 + (cb >> 1)]);
      }
      #pragma unroll
      for (int mi = 0; mi < 4; ++mi)
        #pragma unroll
        for (int ni = 0; ni < 4; ++ni)
          acc[mi][ni] = __builtin_amdgcn_mfma_f32_16x16x32_bf16(a[mi], b[ni], acc[mi][ni], 0, 0, 0);
    }
    __syncthreads();
  }

  const int m_base = bm + wr * 64, n_base = bn + wc * 64;
  if (Crm) {
    #pragma unroll
    for (int mi = 0; mi < 4; ++mi)
      #pragma unroll
      for (int r = 0; r < 4; ++r) {
        int m = m_base + mi * 16 + g * 4 + r;
        #pragma unroll
        for (int ni = 0; ni < 4; ++ni) {
          int n = n_base + ni * 16 + lq;
          Crm[(size_t)m * DD + n] = f2bf(acc[mi][ni][r]);
        }
      }
  }
  if (Cvt) {
    // V^T layout: [b*12+h][d(64)][t(512)]
    #pragma unroll
    for (int mi = 0; mi < 4; ++mi) {
      int m0 = m_base + mi * 16 + g * 4;      // 4 consecutive t
      int bidx = m0 >> 9, t = m0 & 511;
      #pragma unroll
      for (int ni = 0; ni < 4; ++ni) {
        int n = n_base + ni * 16 + lq;
        int hh = n >> 6, d = n & 63;
        u16x4 v4 = { f2bf(acc[mi][ni][0]), f2bf(acc[mi][ni][1]),
                     f2bf(acc[mi][ni][2]), f2bf(acc[mi][ni][3]) };
        *reinterpret_cast<u16x4*>(&Cvt[(((size_t)bidx * HH + hh) * DH + d) * LT + t]) = v4;
      }
    }
  }
  if (Cf) {
    float alpha = 1.0f / (1.0f + __expf(-gl[0]));
    #pragma unroll
    for (int mi = 0; mi < 4; ++mi)
      #pragma unroll
      for (int r = 0; r < 4; ++r) {
        int m = m_base + mi * 16 + g * 4 + r;
        #pragma unroll
        for (int ni = 0; ni < 4; ++ni) {
          int n = n_base + ni * 16 + lq;
          Cf[(size_t)m * DD + n] = resid[(size_t)m * DD + n] + alpha * acc[mi][ni][r];
        }
      }
  }
}

// ---------------- Gate + top-k (bf16 K) ----------------
__global__ __launch_bounds__(512) void gate_topk(const unsigned short* __restrict__ Kbuf,
                                                 const float* __restrict__ hq,
                                                 const int* __restrict__ mask,
                                                 float* __restrict__ keep,
                                                 float* __restrict__ g_h) {
  int bh = blockIdx.x, b = bh / HH, h = bh % HH;
  int l = threadIdx.x;
  __shared__ float s_sc[512];
  __shared__ float s_p[512];
  __shared__ float s_c[64];
  __shared__ float red[8];
  const float scale = 0.125f;
  const unsigned short* kr = Kbuf + ((size_t)(b * LT + l)) * DD + h * DH;
  float sc = 0.0f;
  #pragma unroll
  for (int d0 = 0; d0 < DH; d0 += 8) {
    bf16x8 kk = *reinterpret_cast<const bf16x8*>(kr + d0);
    #pragma unroll
    for (int j = 0; j < 8; j++) sc += bf2f((unsigned short)kk[j]) * hq[h * DH + d0 + j];
  }
  sc *= scale;
  if (mask[b * LT + l] == 0) sc = -INFINITY;
  s_sc[l] = sc;
  __syncthreads();
  float m = sc;
  #pragma unroll
  for (int o = 32; o > 0; o >>= 1) m = fmaxf(m, __shfl_xor(m, o));
  if ((l & 63) == 0) red[l >> 6] = m;
  __syncthreads();
  m = red[0];
  #pragma unroll
  for (int w = 1; w < 8; w++) m = fmaxf(m, red[w]);
  float p = expf(sc - m);
  float ssum = p;
  #pragma unroll
  for (int o = 32; o > 0; o >>= 1) ssum += __shfl_xor(ssum, o);
  __syncthreads();
  if ((l & 63) == 0) red[l >> 6] = ssum;
  __syncthreads();
  float Z = 0.0f;
  #pragma unroll
  for (int w = 0; w < 8; w++) Z += red[w];
  p /= Z;
  s_p[l] = p;
  __syncthreads();
  if (l < 64) {
    float c = 0.0f;
    for (int t = 0; t < LT; t++)
      c += s_p[t] * bf2f(Kbuf[((size_t)(b * LT + t)) * DD + h * DH + l]);
    s_c[l] = c * hq[h * DH + l];
  }
  __syncthreads();
  if (l == 0) {
    float glog = 0.0f;
    for (int d = 0; d < DH; d++) glog += s_c[d];
    glog *= scale;
    g_h[bh] = 1.0f / (1.0f + expf(-glog));
  }
  float my = s_sc[l];
  int cnt = 0;
  for (int j = 0; j < LT; j++) {
    float sj = s_sc[j];
    cnt += (sj > my || (sj == my && j < l)) ? 1 : 0;
  }
  keep[(size_t)bh * LT + l] = (cnt < TOPK) ? 1.0f : 0.0f;
}

// ---------------- MFMA flash attention (bf16 out) ----------------
__global__ __launch_bounds__(256) void attn_mfma(const unsigned short* __restrict__ Qb,
                                                 const unsigned short* __restrict__ Kb,
                                                 const unsigned short* __restrict__ Vt,
                                                 const float* __restrict__ keep,
                                                 const float* __restrict__ g_h,
                                                 const int* __restrict__ mask,
                                                 unsigned short* __restrict__ att) {
  const int bh = blockIdx.y, b = bh / HH, h = bh % HH;
  const int q0 = blockIdx.x * 64;
  const int tid = threadIdx.x;
  const int w = tid >> 6, l = tid & 63;
  const int lq = l & 15, g = l >> 4;

  __shared__ __align__(16) unsigned short Klds[64 * 64];
  __shared__ __align__(16) unsigned short Vlds[64 * 64];
  __shared__ __align__(16) unsigned short Plds[4][16][72];
  __shared__ float kl[64];

  bf16x8 qf0, qf1;
  {
    const unsigned short* qrow =
        Qb + ((size_t)(b * LQ + q0 + w * 16 + lq)) * DD + h * DH + g * 8;
    qf0 = *reinterpret_cast<const bf16x8*>(qrow);
    qf1 = *reinterpret_cast<const bf16x8*>(qrow + 32);
  }

  f32x4 O[4] = {};
  float m_run = -INFINITY, l_run = 0.0f;

  const unsigned short* Kg0 = Kb + ((size_t)(b * LT)) * DD + h * DH;
  const unsigned short* Vg0 = Vt + ((size_t)bh * DH) * LT;

  for (int t0 = 0; t0 < LT; t0 += 64) {
    if (tid < 64) {
      int t = t0 + tid;
      float kv = keep[(size_t)bh * LT + t];
      kl[tid] = (mask[b * LT + t] == 0) ? -1.0f : kv;
    }
    #pragma unroll
    for (int it = 0; it < 2; ++it) {
      int row = w * 16 + it * 8 + (l >> 3);
      int col = ((l & 7) * 16) ^ (((l >> 3) & 7) << 4);
      gload_lds16(Kg0 + (size_t)(t0 + row) * DD + (col >> 1),
                  &Klds[(w * 16 + it * 8) * 64]);
      gload_lds16(Vg0 + (size_t)row * LT + t0 + (col >> 1),
                  &Vlds[(w * 16 + it * 8) * 64]);
    }
    __syncthreads();

    f32x4 S[4];
    #pragma unroll
    for (int kt = 0; kt < 4; ++kt) {
      f32x4 acc = {};
      int row = kt * 16 + lq;
      int c0 = (g * 16) ^ ((row & 7) << 4);
      int c1 = (64 + g * 16) ^ ((row & 7) << 4);
      bf16x8 a0 = *reinterpret_cast<const bf16x8*>(&Klds[row * 64 + (c0 >> 1)]);
      bf16x8 a1 = *reinterpret_cast<const bf16x8*>(&Klds[row * 64 + (c1 >> 1)]);
      acc = __builtin_amdgcn_mfma_f32_16x16x32_bf16(a0, qf0, acc, 0, 0, 0);
      acc = __builtin_amdgcn_mfma_f32_16x16x32_bf16(a1, qf1, acc, 0, 0, 0);
      S[kt] = acc;
    }

    float cmax = -INFINITY;
    #pragma unroll
    for (int kt = 0; kt < 4; ++kt)
      #pragma unroll
      for (int r = 0; r < 4; ++r) {
        float c = kl[kt * 16 + g * 4 + r];
        float s = (c > 0.5f) ? S[kt][r] * 0.125f : (c < -0.5f ? -INFINITY : 0.0f);
        cmax = fmaxf(cmax, s);
      }
    cmax = fmaxf(cmax, __shfl_xor(cmax, 16));
    cmax = fmaxf(cmax, __shfl_xor(cmax, 32));
    float m_new = fmaxf(m_run, cmax);
    float fac = (m_new == -INFINITY) ? 1.0f : __expf(m_run - m_new);

    float psum = 0.0f;
    #pragma unroll
    for (int kt = 0; kt < 4; ++kt)
      #pragma unroll
      for (int r = 0; r < 4; ++r) {
        int key = kt * 16 + g * 4 + r;
        float c = kl[key];
        float s = (c > 0.5f) ? S[kt][r] * 0.125f : (c < -0.5f ? -INFINITY : 0.0f);
        float p = __expf(s - m_new);
        psum += p;
        Plds[w][lq][key] = f2bf((c > 0.5f) ? p : 0.0f);
      }
    psum += __shfl_xor(psum, 16);
    psum += __shfl_xor(psum, 32);
    l_run = l_run * fac + psum;
    m_run = m_new;

    float facO[4];
    #pragma unroll
    for (int r = 0; r < 4; ++r) facO[r] = __shfl(fac, g * 4 + r);
    #pragma unroll
    for (int dt = 0; dt < 4; ++dt)
      #pragma unroll
      for (int r = 0; r < 4; ++r) O[dt][r] *= facO[r];

    __syncthreads();

    #pragma unroll
    for (int ks = 0; ks < 2; ++ks) {
      bf16x8 pa = *reinterpret_cast<const bf16x8*>(&Plds[w][lq][ks * 32 + g * 8]);
      #pragma unroll
      for (int dt = 0; dt < 4; ++dt) {
        int row = dt * 16 + lq;
        int cb = (ks * 64 + g * 16) ^ ((row & 7) << 4);
        bf16x8 vb = *reinterpret_cast<const bf16x8*>(&Vlds[row * 64 + (cb >> 1)]);
        O[dt] = __builtin_amdgcn_mfma_f32_16x16x32_bf16(pa, vb, O[dt], 0, 0, 0);
      }
    }
    __syncthreads();
  }

  float inv = 1.0f / l_run;
  float invl[4];
  #pragma unroll
  for (int r = 0; r < 4; ++r) invl[r] = __shfl(inv, g * 4 + r);
  float gh = g_h[bh];
  #pragma unroll
  for (int dt = 0; dt < 4; ++dt)
    #pragma unroll
    for (int r = 0; r < 4; ++r) {
      int q = q0 + w * 16 + g * 4 + r;
      att[((size_t)(b * LQ + q)) * DD + h * DH + dt * 16 + lq] =
          f2bf(O[dt][r] * invl[r] * gh);
    }
}

extern "C" void kernel_launch(void* const* d_in, const int* in_sizes, int n_in,
                              void* d_out, int out_size, void* d_ws, size_t ws_size,
                              hipStream_t stream) {
  const float* x_q      = (const float*)d_in[0];
  const float* x_kv     = (const float*)d_in[1];
  const int*   mask     = (const int*)d_in[2];
  const float* wq       = (const float*)d_in[3];
  const float* wk       = (const float*)d_in[4];
  const float* wv       = (const float*)d_in[5];
  const float* wo       = (const float*)d_in[6];
  const float* ln_q_g   = (const float*)d_in[7];
  const float* ln_q_b   = (const float*)d_in[8];
  const float* ln_kv_g  = (const float*)d_in[9];
  const float* ln_kv_b  = (const float*)d_in[10];
  const float* hq       = (const float*)d_in[11];
  const float* resid_l  = (const float*)d_in[12];
  float* out = (float*)d_out;
  float* ws  = (float*)d_ws;

  unsigned short* xqb  = (unsigned short*)(ws + XQBF);
  unsigned short* xkvb = (unsigned short*)(ws + XKVBF);
  unsigned short* wqb  = (unsigned short*)(ws + WQB);
  unsigned short* wkb  = (unsigned short*)(ws + WKB);
  unsigned short* wvb  = (unsigned short*)(ws + WVB);
  unsigned short* wob  = (unsigned short*)(ws + WOB);
  unsigned short* QBF  = (unsigned short*)(ws + QBFo);
  unsigned short* KBF  = (unsigned short*)(ws + KBFo);
  unsigned short* VTB  = (unsigned short*)(ws + VTBo);
  unsigned short* ABF  = (unsigned short*)(ws + ABFo);

  const int WN = DD * DD;  // 589824
  conv_bf16<<<dim3(WN / 1024), dim3(256), 0, stream>>>(wq, wqb, WN);
  conv_bf16<<<dim3(WN / 1024), dim3(256), 0, stream>>>(wk, wkb, WN);
  conv_bf16<<<dim3(WN / 1024), dim3(256), 0, stream>>>(wv, wvb, WN);
  conv_bf16<<<dim3(WN / 1024), dim3(256), 0, stream>>>(wo, wob, WN);

  ln_bf16<<<dim3(BB * LQ), dim3(256), 0, stream>>>(x_q, ln_q_g, ln_q_b, xqb);
  ln_bf16<<<dim3(BB * LT), dim3(256), 0, stream>>>(x_kv, ln_kv_g, ln_kv_b, xkvb);

  gemm_bf16<<<dim3(6, 72), dim3(256), 0, stream>>>(xqb, wqb, BB * LQ, DD,
                                                   QBF, nullptr, nullptr, nullptr, nullptr);
  gemm_bf16<<<dim3(6, 64), dim3(256), 0, stream>>>(xkvb, wkb, BB * LT, DD,
                                                   KBF, nullptr, nullptr, nullptr, nullptr);
  gemm_bf16<<<dim3(6, 64), dim3(256), 0, stream>>>(xkvb, wvb, BB * LT, DD,
                                                   nullptr, VTB, nullptr, nullptr, nullptr);

  gate_topk<<<dim3(BB * HH), dim3(512), 0, stream>>>(KBF, hq, mask, ws + KEEP, ws + GH);

  attn_mfma<<<dim3(LQ / 64, BB * HH), dim3(256), 0, stream>>>(QBF, KBF, VTB,
                                                              ws + KEEP, ws + GH, mask, ABF);

  gemm_bf16<<<dim3(6, 72), dim3(256), 0, stream>>>(ABF, wob, BB * LQ, DD,
                                                   nullptr, nullptr, out, x_q, resid_l);
}

// Round 4
// 164.536 us; speedup vs baseline: 8.4947x; 1.2755x over previous
//
#include <hip/hip_runtime.h>
#include <math.h>

// Problem constants
#define BB 16
#define LQ 576
#define LT 512
#define DD 768
#define HH 12
#define DH 64
#define TOPK 64

typedef __attribute__((ext_vector_type(8))) short bf16x8;
typedef __attribute__((ext_vector_type(4))) float f32x4;
typedef __attribute__((ext_vector_type(4))) unsigned short u16x4;

// Workspace layout (float offsets)
static constexpr size_t XQBF  = 0;          // 9216*768 bf16 (xq_n; reused as attn-out ABF)
static constexpr size_t XKVBF = 3538944;    // 8192*768 bf16
static constexpr size_t WQB   = 6684672;    // 768*768 bf16
static constexpr size_t WKB   = 6979584;    // wk bf16 (contiguous with WVB -> [1536][768])
static constexpr size_t WVB   = 7274496;
static constexpr size_t WOB   = 7569408;
static constexpr size_t QBFo  = 7864320;    // 9216*768 bf16 (pre-scaled by 0.125)
static constexpr size_t KBFo  = 11403264;   // 8192*768 bf16
static constexpr size_t VBFo  = 14548992;   // 8192*768 bf16 row-major
static constexpr size_t IDXo  = 17694720;   // 192*64 int
static constexpr size_t VBIA  = 17707008;   // 192*64 f32 (0 or -inf)
static constexpr size_t NDVo  = 17719296;   // 192 f32
static constexpr size_t GHo   = 17719488;   // 192 f32
static constexpr size_t KCo   = 17719680;   // 192*64*64 bf16
static constexpr size_t VCTo  = 18112896;   // 192*64*64 bf16 (V^T compact [d][j])

__device__ inline unsigned short f2bf(float f) {
  union { float f; unsigned u; } v; v.f = f;
  unsigned r = v.u + 0x7FFFu + ((v.u >> 16) & 1u);
  return (unsigned short)(r >> 16);
}
__device__ inline float bf2f(unsigned short u) {
  union { unsigned u; float f; } v; v.u = ((unsigned)u) << 16;
  return v.f;
}
__device__ inline void gload_lds16(const void* src, void* dst) {
  __builtin_amdgcn_global_load_lds((const __attribute__((address_space(1))) void*)src,
                                   (__attribute__((address_space(3))) void*)dst, 16, 0, 0);
}

// ---------------- LayerNorm -> bf16 ----------------
__global__ __launch_bounds__(256) void ln_bf16(const float* __restrict__ x,
                                               const float* __restrict__ gg,
                                               const float* __restrict__ bb,
                                               unsigned short* __restrict__ y) {
  int row = blockIdx.x;
  const float* xr = x + (size_t)row * DD;
  unsigned short* yr = y + (size_t)row * DD;
  int t = threadIdx.x;
  float v0 = xr[t], v1 = xr[t + 256], v2 = xr[t + 512];
  __shared__ float red[4];
  float s = v0 + v1 + v2;
  #pragma unroll
  for (int o = 32; o > 0; o >>= 1) s += __shfl_xor(s, o);
  if ((t & 63) == 0) red[t >> 6] = s;
  __syncthreads();
  float m = (red[0] + red[1] + red[2] + red[3]) * (1.0f / 768.0f);
  float d0 = v0 - m, d1 = v1 - m, d2 = v2 - m;
  float s2 = d0 * d0 + d1 * d1 + d2 * d2;
  #pragma unroll
  for (int o = 32; o > 0; o >>= 1) s2 += __shfl_xor(s2, o);
  __syncthreads();
  if ((t & 63) == 0) red[t >> 6] = s2;
  __syncthreads();
  float var = (red[0] + red[1] + red[2] + red[3]) * (1.0f / 768.0f);
  float rs = rsqrtf(var + 1e-5f);
  yr[t]       = f2bf(d0 * rs * gg[t]       + bb[t]);
  yr[t + 256] = f2bf(d1 * rs * gg[t + 256] + bb[t + 256]);
  yr[t + 512] = f2bf(d2 * rs * gg[t + 512] + bb[t + 512]);
}

// ---------------- 4x f32 -> bf16 weight convert, one launch ----------------
__global__ __launch_bounds__(256) void conv4(const float* __restrict__ s0, const float* __restrict__ s1,
                                             const float* __restrict__ s2, const float* __restrict__ s3,
                                             unsigned short* d0, unsigned short* d1,
                                             unsigned short* d2, unsigned short* d3) {
  const float* s; unsigned short* d;
  switch (blockIdx.y) {
    case 0: s = s0; d = d0; break;
    case 1: s = s1; d = d1; break;
    case 2: s = s2; d = d2; break;
    default: s = s3; d = d3; break;
  }
  int i = (blockIdx.x * 256 + threadIdx.x) * 4;
  float4 v = *reinterpret_cast<const float4*>(&s[i]);
  u16x4 o = { f2bf(v.x), f2bf(v.y), f2bf(v.z), f2bf(v.w) };
  *reinterpret_cast<u16x4*>(&d[i]) = o;
}

// ---------------- bf16 MFMA GEMM: C = A[M,K] * W[Nrows,K]^T ----------------
// 128x128 tile, BK=64, 4 waves (2x2), 4x4 fragments. Split row-major output at n=768.
__global__ __launch_bounds__(256) void gemm_bf16(const unsigned short* __restrict__ A,
                                                 const unsigned short* __restrict__ W,
                                                 int M, int K,
                                                 unsigned short* __restrict__ Crm,
                                                 unsigned short* __restrict__ Crm2,
                                                 float* __restrict__ Cf,
                                                 const float* __restrict__ resid,
                                                 const float* __restrict__ gl,
                                                 float outScale) {
  __shared__ __align__(16) unsigned short As[128 * 64];
  __shared__ __align__(16) unsigned short Bs[128 * 64];
  const int tid = threadIdx.x;
  const int w = tid >> 6, l = tid & 63;
  const int bm = blockIdx.y * 128, bn = blockIdx.x * 128;
  const int wr = w >> 1, wc = w & 1;
  const int lq = l & 15, g = l >> 4;
  f32x4 acc[4][4] = {};
  const int srow = l >> 3;
  const int scol = ((l & 7) * 16) ^ ((srow & 7) << 4);

  for (int k0 = 0; k0 < K; k0 += 64) {
    #pragma unroll
    for (int it = 0; it < 4; ++it) {
      int rbase = it * 32 + w * 8;
      gload_lds16(A + (size_t)(bm + rbase + srow) * K + k0 + (scol >> 1), &As[rbase * 64]);
      gload_lds16(W + (size_t)(bn + rbase + srow) * K + k0 + (scol >> 1), &Bs[rbase * 64]);
    }
    __syncthreads();
    #pragma unroll
    for (int ks = 0; ks < 2; ++ks) {
      bf16x8 a[4], b[4];
      #pragma unroll
      for (int mi = 0; mi < 4; ++mi) {
        int row = wr * 64 + mi * 16 + lq;
        int cb = (ks * 64 + g * 16) ^ ((row & 7) << 4);
        a[mi] = *reinterpret_cast<const bf16x8*>(&As[row * 64 + (cb >> 1)]);
      }
      #pragma unroll
      for (int ni = 0; ni < 4; ++ni) {
        int row = wc * 64 + ni * 16 + lq;
        int cb = (ks * 64 + g * 16) ^ ((row & 7) << 4);
        b[ni] = *reinterpret_cast<const bf16x8*>(&Bs[row * 64 + (cb >> 1)]);
      }
      #pragma unroll
      for (int mi = 0; mi < 4; ++mi)
        #pragma unroll
        for (int ni = 0; ni < 4; ++ni)
          acc[mi][ni] = __builtin_amdgcn_mfma_f32_16x16x32_bf16(a[mi], b[ni], acc[mi][ni], 0, 0, 0);
    }
    __syncthreads();
  }

  const int m_base = bm + wr * 64, n_base = bn + wc * 64;
  if (Crm) {
    #pragma unroll
    for (int mi = 0; mi < 4; ++mi)
      #pragma unroll
      for (int r = 0; r < 4; ++r) {
        int m = m_base + mi * 16 + g * 4 + r;
        #pragma unroll
        for (int ni = 0; ni < 4; ++ni) {
          int n = n_base + ni * 16 + lq;
          unsigned short v = f2bf(acc[mi][ni][r] * outScale);
          if (!Crm2 || n < DD) Crm[(size_t)m * DD + n] = v;
          else                 Crm2[(size_t)m * DD + n - DD] = v;
        }
      }
  }
  if (Cf) {
    float alpha = 1.0f / (1.0f + __expf(-gl[0]));
    #pragma unroll
    for (int mi = 0; mi < 4; ++mi)
      #pragma unroll
      for (int r = 0; r < 4; ++r) {
        int m = m_base + mi * 16 + g * 4 + r;
        #pragma unroll
        for (int ni = 0; ni < 4; ++ni) {
          int n = n_base + ni * 16 + lq;
          Cf[(size_t)m * DD + n] = resid[(size_t)m * DD + n] + alpha * acc[mi][ni][r];
        }
      }
  }
}

// ---------------- Gate + top-k: emits idx list (rank order), validity bias, n_dropped_valid ----------------
__global__ __launch_bounds__(512) void gate_topk(const unsigned short* __restrict__ Kbuf,
                                                 const float* __restrict__ hq,
                                                 const int* __restrict__ mask,
                                                 int* __restrict__ idxo,
                                                 float* __restrict__ vbias,
                                                 float* __restrict__ ndv,
                                                 float* __restrict__ g_h) {
  int bh = blockIdx.x, b = bh / HH, h = bh % HH;
  int l = threadIdx.x;
  __shared__ float s_sc[512];
  __shared__ float s_p[512];
  __shared__ float s_c[64];
  __shared__ float red[8];
  __shared__ int wred[8];
  const float scale = 0.125f;
  const unsigned short* kr = Kbuf + ((size_t)(b * LT + l)) * DD + h * DH;
  float sc = 0.0f;
  #pragma unroll
  for (int d0 = 0; d0 < DH; d0 += 8) {
    bf16x8 kk = *reinterpret_cast<const bf16x8*>(kr + d0);
    #pragma unroll
    for (int j = 0; j < 8; j++) sc += bf2f((unsigned short)kk[j]) * hq[h * DH + d0 + j];
  }
  sc *= scale;
  bool maskv = (mask[b * LT + l] != 0);
  if (!maskv) sc = -INFINITY;
  s_sc[l] = sc;
  __syncthreads();
  float m = sc;
  #pragma unroll
  for (int o = 32; o > 0; o >>= 1) m = fmaxf(m, __shfl_xor(m, o));
  if ((l & 63) == 0) red[l >> 6] = m;
  __syncthreads();
  m = red[0];
  #pragma unroll
  for (int w = 1; w < 8; w++) m = fmaxf(m, red[w]);
  float p = expf(sc - m);
  float ssum = p;
  #pragma unroll
  for (int o = 32; o > 0; o >>= 1) ssum += __shfl_xor(ssum, o);
  __syncthreads();
  if ((l & 63) == 0) red[l >> 6] = ssum;
  __syncthreads();
  float Z = 0.0f;
  #pragma unroll
  for (int w = 0; w < 8; w++) Z += red[w];
  p /= Z;
  s_p[l] = p;
  __syncthreads();
  if (l < 64) {
    float c = 0.0f;
    for (int t = 0; t < LT; t++)
      c += s_p[t] * bf2f(Kbuf[((size_t)(b * LT + t)) * DD + h * DH + l]);
    s_c[l] = c * hq[h * DH + l];
  }
  __syncthreads();
  if (l == 0) {
    float glog = 0.0f;
    for (int d = 0; d < DH; d++) glog += s_c[d];
    glog *= scale;
    g_h[bh] = 1.0f / (1.0f + expf(-glog));
  }
  // stable rank (matches jax.lax.top_k tie-breaking)
  float my = s_sc[l];
  int cnt = 0;
  for (int j = 0; j < LT; j++) {
    float sj = s_sc[j];
    cnt += (sj > my || (sj == my && j < l)) ? 1 : 0;
  }
  if (cnt < TOPK) {
    idxo[bh * TOPK + cnt] = l;
    vbias[bh * TOPK + cnt] = maskv ? 0.0f : -INFINITY;
  }
  int dv = (maskv && cnt >= TOPK) ? 1 : 0;
  unsigned long long bal = __ballot(dv);
  if ((l & 63) == 0) wred[l >> 6] = __popcll(bal);
  __syncthreads();
  if (l == 0) {
    int nd = 0;
    #pragma unroll
    for (int w = 0; w < 8; w++) nd += wred[w];
    ndv[bh] = (float)nd;
  }
}

// ---------------- Compact K/V^T for the kept 64 tokens per (b,h) ----------------
__global__ __launch_bounds__(256) void compact_kv(const unsigned short* __restrict__ KBF,
                                                  const unsigned short* __restrict__ VBF,
                                                  const int* __restrict__ idxo,
                                                  unsigned short* __restrict__ KC,
                                                  unsigned short* __restrict__ VCT) {
  int bh = blockIdx.x, b = bh / HH, h = bh % HH;
  int tid = threadIdx.x;
  __shared__ int sidx[64];
  __shared__ __align__(16) unsigned short vt[64][80];
  if (tid < 64) sidx[tid] = idxo[bh * TOPK + tid];
  __syncthreads();
  #pragma unroll
  for (int it = 0; it < 2; ++it) {
    int j = it * 32 + (tid >> 3);
    int c = (tid & 7) * 8;
    size_t src = ((size_t)(b * LT) + sidx[j]) * DD + h * DH + c;
    bf16x8 kv = *reinterpret_cast<const bf16x8*>(&KBF[src]);
    *reinterpret_cast<bf16x8*>(&KC[(size_t)bh * 4096 + j * 64 + c]) = kv;
    bf16x8 vv = *reinterpret_cast<const bf16x8*>(&VBF[src]);
    *reinterpret_cast<bf16x8*>(&vt[j][c]) = vv;
  }
  __syncthreads();
  #pragma unroll
  for (int it = 0; it < 2; ++it) {
    int d = it * 32 + (tid >> 3);
    int jc = (tid & 7) * 8;
    bf16x8 o;
    #pragma unroll
    for (int i = 0; i < 8; i++) o[i] = (short)vt[jc + i][d];
    *reinterpret_cast<bf16x8*>(&VCT[(size_t)bh * 4096 + d * 64 + jc]) = o;
  }
}

// ---------------- Top-k attention: single 64-key tile, closed-form dropped-mass correction ----------------
__global__ __launch_bounds__(256) void attn_topk(const unsigned short* __restrict__ Qb,
                                                 const unsigned short* __restrict__ KC,
                                                 const unsigned short* __restrict__ VCT,
                                                 const float* __restrict__ vbias,
                                                 const float* __restrict__ ndv,
                                                 const float* __restrict__ g_h,
                                                 unsigned short* __restrict__ att) {
  const int bh = blockIdx.y, b = bh / HH, h = bh % HH;
  const int q0 = blockIdx.x * 64;
  const int tid = threadIdx.x;
  const int w = tid >> 6, l = tid & 63;
  const int lq = l & 15, g = l >> 4;

  __shared__ __align__(16) unsigned short Klds[64 * 64];
  __shared__ __align__(16) unsigned short Vlds[64 * 64];
  __shared__ float svb[64];

  const int srow = l >> 3;
  const int scol = ((l & 7) * 16) ^ ((srow & 7) << 4);
  #pragma unroll
  for (int it = 0; it < 2; ++it) {
    int rbase = w * 16 + it * 8;
    gload_lds16(KC  + (size_t)bh * 4096 + (rbase + srow) * 64 + (scol >> 1), &Klds[rbase * 64]);
    gload_lds16(VCT + (size_t)bh * 4096 + (rbase + srow) * 64 + (scol >> 1), &Vlds[rbase * 64]);
  }
  if (tid < 64) svb[tid] = vbias[bh * TOPK + tid];

  // Q fragments (pre-scaled by 0.125 in Q-GEMM)
  bf16x8 qf0, qf1;
  {
    const unsigned short* qrow =
        Qb + ((size_t)(b * LQ + q0 + w * 16 + lq)) * DD + h * DH + g * 8;
    qf0 = *reinterpret_cast<const bf16x8*>(qrow);
    qf1 = *reinterpret_cast<const bf16x8*>(qrow + 32);
  }
  __syncthreads();

  // S^T[64 kept, 16 q]
  f32x4 S[4];
  #pragma unroll
  for (int kt = 0; kt < 4; ++kt) {
    f32x4 acc = {};
    int row = kt * 16 + lq;
    int c0 = (g * 16) ^ ((row & 7) << 4);
    int c1 = (64 + g * 16) ^ ((row & 7) << 4);
    bf16x8 a0 = *reinterpret_cast<const bf16x8*>(&Klds[row * 64 + (c0 >> 1)]);
    bf16x8 a1 = *reinterpret_cast<const bf16x8*>(&Klds[row * 64 + (c1 >> 1)]);
    acc = __builtin_amdgcn_mfma_f32_16x16x32_bf16(a0, qf0, acc, 0, 0, 0);
    acc = __builtin_amdgcn_mfma_f32_16x16x32_bf16(a1, qf1, acc, 0, 0, 0);
    S[kt] = acc;
  }

  // single-pass softmax over 64 kept keys + dropped-mass correction
  float s_v[16];
  float mx = -INFINITY;
  #pragma unroll
  for (int kt = 0; kt < 4; ++kt)
    #pragma unroll
    for (int r = 0; r < 4; ++r) {
      float s = S[kt][r] + svb[kt * 16 + g * 4 + r];
      s_v[kt * 4 + r] = s;
      mx = fmaxf(mx, s);
    }
  mx = fmaxf(mx, __shfl_xor(mx, 16));
  mx = fmaxf(mx, __shfl_xor(mx, 32));
  float nd = ndv[bh];
  float m2 = (nd > 0.0f) ? fmaxf(mx, 0.0f) : mx;

  float psum = 0.0f;
  unsigned short pb[16];
  #pragma unroll
  for (int i = 0; i < 16; ++i) {
    float p = __expf(s_v[i] - m2);
    psum += p;
    pb[i] = f2bf(p);
  }
  psum += __shfl_xor(psum, 16);
  psum += __shfl_xor(psum, 32);
  float Z = psum + nd * __expf(-m2);
  float inv = 1.0f / Z;

  // P fragments in-register (matched logical-k map with V^T reads)
  bf16x8 pa0, pa1;
  #pragma unroll
  for (int j = 0; j < 8; ++j) { pa0[j] = (short)pb[j]; pa1[j] = (short)pb[8 + j]; }

  f32x4 O[4] = {};
  #pragma unroll
  for (int dt = 0; dt < 4; ++dt) {
    int r = dt * 16 + lq;
    int swz = (r & 7) << 4;
    #pragma unroll
    for (int ks = 0; ks < 2; ++ks) {
      int cl = (64 * ks + g * 8) ^ swz;
      int ch = (64 * ks + 32 + g * 8) ^ swz;
      u16x4 lo = *reinterpret_cast<const u16x4*>(&Vlds[r * 64 + (cl >> 1)]);
      u16x4 hi = *reinterpret_cast<const u16x4*>(&Vlds[r * 64 + (ch >> 1)]);
      bf16x8 vb = { (short)lo[0], (short)lo[1], (short)lo[2], (short)lo[3],
                    (short)hi[0], (short)hi[1], (short)hi[2], (short)hi[3] };
      O[dt] = __builtin_amdgcn_mfma_f32_16x16x32_bf16(ks == 0 ? pa0 : pa1, vb, O[dt], 0, 0, 0);
    }
  }

  float invl[4];
  #pragma unroll
  for (int r = 0; r < 4; ++r) invl[r] = __shfl(inv, g * 4 + r);
  float gh = g_h[bh];
  #pragma unroll
  for (int dt = 0; dt < 4; ++dt)
    #pragma unroll
    for (int r = 0; r < 4; ++r) {
      int q = q0 + w * 16 + g * 4 + r;
      att[((size_t)(b * LQ + q)) * DD + h * DH + dt * 16 + lq] =
          f2bf(O[dt][r] * invl[r] * gh);
    }
}

extern "C" void kernel_launch(void* const* d_in, const int* in_sizes, int n_in,
                              void* d_out, int out_size, void* d_ws, size_t ws_size,
                              hipStream_t stream) {
  const float* x_q      = (const float*)d_in[0];
  const float* x_kv     = (const float*)d_in[1];
  const int*   mask     = (const int*)d_in[2];
  const float* wq       = (const float*)d_in[3];
  const float* wk       = (const float*)d_in[4];
  const float* wv       = (const float*)d_in[5];
  const float* wo       = (const float*)d_in[6];
  const float* ln_q_g   = (const float*)d_in[7];
  const float* ln_q_b   = (const float*)d_in[8];
  const float* ln_kv_g  = (const float*)d_in[9];
  const float* ln_kv_b  = (const float*)d_in[10];
  const float* hq       = (const float*)d_in[11];
  const float* resid_l  = (const float*)d_in[12];
  float* out = (float*)d_out;
  float* ws  = (float*)d_ws;

  unsigned short* xqb  = (unsigned short*)(ws + XQBF);
  unsigned short* xkvb = (unsigned short*)(ws + XKVBF);
  unsigned short* wqb  = (unsigned short*)(ws + WQB);
  unsigned short* wkb  = (unsigned short*)(ws + WKB);   // [1536][768] with wvb
  unsigned short* wvb  = (unsigned short*)(ws + WVB);
  unsigned short* wob  = (unsigned short*)(ws + WOB);
  unsigned short* QBF  = (unsigned short*)(ws + QBFo);
  unsigned short* KBF  = (unsigned short*)(ws + KBFo);
  unsigned short* VBF  = (unsigned short*)(ws + VBFo);
  int*            IDX  = (int*)(ws + IDXo);
  unsigned short* KC   = (unsigned short*)(ws + KCo);
  unsigned short* VCT  = (unsigned short*)(ws + VCTo);
  unsigned short* ABF  = xqb;   // reuse xq_n slot after Q-GEMM

  conv4<<<dim3(576, 4), dim3(256), 0, stream>>>(wq, wk, wv, wo, wqb, wkb, wvb, wob);

  ln_bf16<<<dim3(BB * LQ), dim3(256), 0, stream>>>(x_q, ln_q_g, ln_q_b, xqb);
  ln_bf16<<<dim3(BB * LT), dim3(256), 0, stream>>>(x_kv, ln_kv_g, ln_kv_b, xkvb);

  // Q projection (scale 1/8 folded in)
  gemm_bf16<<<dim3(6, 72), dim3(256), 0, stream>>>(xqb, wqb, BB * LQ, DD,
                                                   QBF, nullptr, nullptr, nullptr, nullptr, 0.125f);
  // fused K+V projection (W = wk||wv, N=1536)
  gemm_bf16<<<dim3(12, 64), dim3(256), 0, stream>>>(xkvb, wkb, BB * LT, DD,
                                                    KBF, VBF, nullptr, nullptr, nullptr, 1.0f);

  gate_topk<<<dim3(BB * HH), dim3(512), 0, stream>>>(KBF, hq, mask, IDX,
                                                     ws + VBIA, ws + NDVo, ws + GHo);

  compact_kv<<<dim3(BB * HH), dim3(256), 0, stream>>>(KBF, VBF, IDX, KC, VCT);

  attn_topk<<<dim3(LQ / 64, BB * HH), dim3(256), 0, stream>>>(QBF, KC, VCT,
                                                              ws + VBIA, ws + NDVo, ws + GHo, ABF);

  gemm_bf16<<<dim3(6, 72), dim3(256), 0, stream>>>(ABF, wob, BB * LQ, DD,
                                                   nullptr, nullptr, out, x_q, resid_l, 1.0f);
}